// Round 21
// baseline (145.909 us; speedup 1.0000x reference)
//
#include <hip/hip_runtime.h>

#define LOG2E 1.4426950408889634f
#define SCALE (2.0f * LOG2E)

__device__ __forceinline__ float fast_exp2(float x) { return __builtin_amdgcn_exp2f(x); }
__device__ __forceinline__ float fast_rcp(float x)  { return __builtin_amdgcn_rcpf(x); }

typedef __attribute__((ext_vector_type(8))) short bf16x8;
typedef __attribute__((ext_vector_type(4))) float f32x4;

__device__ __forceinline__ void cvt_hilo8(const float* vv, ushort* hi8, ushort* lo8) {
#pragma unroll
    for (int j = 0; j < 8; ++j) {
        unsigned u32 = __float_as_uint(vv[j]);
        unsigned h = (u32 + 0x7FFF + ((u32 >> 16) & 1)) >> 16;   // RN bf16
        hi8[j] = (ushort)h;
        float lo = vv[j] - __uint_as_float(h << 16);
        unsigned ul = __float_as_uint(lo);
        lo8[j] = (ushort)((ul + 0x7FFF + ((ul >> 16) & 1)) >> 16);
    }
}

// ---------------- stage 0+1 fused: MFMA GEMM direct from f32 (R20, unchanged) ----------
__global__ __launch_bounds__(512) void mfma_gemm(const float* __restrict__ inputs,
                                                 const float* __restrict__ attn_W,
                                                 const float* __restrict__ attn_b,
                                                 float* __restrict__ E1,
                                                 float* __restrict__ E2) {
    const int xcd = blockIdx.x & 7;
    const int idx = blockIdx.x >> 3;
    const int mb  = xcd * 2 + (idx >> 4);
    const int nb  = idx & 15;
    __shared__ ushort lds[24576];
    ushort* const Ahi = lds;
    ushort* const Alo = lds + 8192;
    ushort* const Bhi = lds + 16384;
    ushort* const Blo = lds + 20480;

    const int t = threadIdx.x;
    const int lane = t & 63, w = t >> 6;
    const int wr = w >> 1, wc = w & 1;

    const int arow0 = t >> 3, ak8 = t & 7;
    const int arow1 = (t + 512) >> 3;
    const int m0 = mb * 128 + arow0;
    const int m1 = mb * 128 + arow1;
    const float* asrc0 = inputs + (long)((m0 & 255) * 8 + (m0 >> 8)) * 512 + ak8 * 8;
    const float* asrc1 = inputs + (long)((m1 & 255) * 8 + (m1 >> 8)) * 512 + ak8 * 8;
    const int nloc = t >> 3, bk8 = t & 7;
    const int ngl = nb * 64 + nloc;
    const float* bsrc = attn_W + (long)(ngl & 511) * 1024 + (ngl >> 9) * 512 + bk8 * 8;

    const int aoff0 = (arow0 >> 6) * 4096 + (ak8 >> 2) * 2048 + ((arow0 & 63) >> 4) * 512 +
                      ((ak8 & 3) * 16 + (arow0 & 15)) * 8;
    const int aoff1 = (arow1 >> 6) * 4096 + (ak8 >> 2) * 2048 + ((arow1 & 63) >> 4) * 512 +
                      ((ak8 & 3) * 16 + (arow1 & 15)) * 8;
    const int boff  = (bk8 >> 2) * 2048 + (nloc >> 4) * 512 +
                      ((bk8 & 3) * 16 + (nloc & 15)) * 8;

    f32x4 acc[2][2];
#pragma unroll
    for (int i = 0; i < 2; ++i)
#pragma unroll
        for (int j = 0; j < 2; ++j)
            acc[i][j] = (f32x4){0.f, 0.f, 0.f, 0.f};

    float ra0[8], ra1[8], rb[8];
#define LOADF(ss)                                                              \
    {                                                                          \
        *(float4*)&ra0[0] = *(const float4*)(asrc0 + (ss) * 64);               \
        *(float4*)&ra0[4] = *(const float4*)(asrc0 + (ss) * 64 + 4);           \
        *(float4*)&ra1[0] = *(const float4*)(asrc1 + (ss) * 64);               \
        *(float4*)&ra1[4] = *(const float4*)(asrc1 + (ss) * 64 + 4);           \
        *(float4*)&rb[0]  = *(const float4*)(bsrc  + (ss) * 64);               \
        *(float4*)&rb[4]  = *(const float4*)(bsrc  + (ss) * 64 + 4);           \
    }

    LOADF(0);

    for (int ss = 0; ss < 8; ++ss) {
        __syncthreads();
        {
            ushort h8[8], l8[8];
            cvt_hilo8(ra0, h8, l8);
            *(uint4*)&Ahi[aoff0] = *(const uint4*)h8;
            *(uint4*)&Alo[aoff0] = *(const uint4*)l8;
            cvt_hilo8(ra1, h8, l8);
            *(uint4*)&Ahi[aoff1] = *(const uint4*)h8;
            *(uint4*)&Alo[aoff1] = *(const uint4*)l8;
            cvt_hilo8(rb, h8, l8);
            *(uint4*)&Bhi[boff] = *(const uint4*)h8;
            *(uint4*)&Blo[boff] = *(const uint4*)l8;
        }
        if (ss < 7) LOADF(ss + 1);
        __syncthreads();

#pragma unroll
        for (int pass = 0; pass < 3; ++pass) {
            const ushort* Ab = (pass == 1) ? Alo : Ahi;
            const ushort* Bb = (pass == 2) ? Blo : Bhi;
#pragma unroll
            for (int ks = 0; ks < 2; ++ks) {
                bf16x8 a[2], b[2];
                const int abase = (wr >> 1) * 4096 + ks * 2048 + (wr & 1) * 1024 + lane * 8;
                const int bbase = ks * 2048 + wc * 1024 + lane * 8;
                a[0] = *(const bf16x8*)&Ab[abase];
                a[1] = *(const bf16x8*)&Ab[abase + 512];
                b[0] = *(const bf16x8*)&Bb[bbase];
                b[1] = *(const bf16x8*)&Bb[bbase + 512];
#pragma unroll
                for (int mf = 0; mf < 2; ++mf)
#pragma unroll
                    for (int nf = 0; nf < 2; ++nf)
                        acc[mf][nf] = __builtin_amdgcn_mfma_f32_16x16x32_bf16(
                            a[mf], b[nf], acc[mf][nf], 0, 0, 0);
            }
        }
    }
#undef LOADF

#pragma unroll
    for (int nf = 0; nf < 2; ++nf) {
        int n = nb * 64 + wc * 32 + nf * 16 + (lane & 15);
        const bool isE1 = (n < 512);
        float* dst = isE1 ? E1 : E2;
        int o = n & 511;
        float bias = isE1 ? attn_b[o] : 0.0f;
#pragma unroll
        for (int mf = 0; mf < 2; ++mf) {
            int ml = mb * 128 + wr * 32 + mf * 16 + ((lane >> 4) << 2);
            int bb = ml >> 8, l = ml & 255;
            long rowoff = ((long)(bb * 8 + (l >> 5)) * 512 + o) * 32 + (l & 31);
#pragma unroll
            for (int r = 0; r < 4; ++r)
                dst[rowoff + r] = fast_exp2(SCALE * (acc[mf][nf][r] + bias));
        }
    }
}

// ---------------- stage 2: energy v4 + last-block fused softmax ----------------
// EP[s][b][i][j] partials as before. After writing, each block fences + bumps a
// per-(b,tj) counter; the 16th (last) arriver performs the softmax for its 64
// columns. No spinning -> no deadlock possible.
__global__ __launch_bounds__(256) void energy_kernel(const float* __restrict__ E1,
                                                     const float* __restrict__ E2,
                                                     const float* __restrict__ sW,
                                                     float* __restrict__ EP,
                                                     unsigned* __restrict__ cnt,
                                                     float* __restrict__ out) {
    const int bid = blockIdx.x;       // 512 = s(4) b(8) ti(4) tj(4)
    const int tj = bid & 3;
    const int ti = (bid >> 2) & 3;
    const int b  = (bid >> 4) & 7;
    const int s  = bid >> 7;
    __shared__ float As[32 * 64];
    __shared__ float Bs[32 * 64];
    __shared__ float csh[128];
    __shared__ unsigned lastflag;

    const int t = threadIdx.x;
    const int tx = t & 15, ty = t >> 4;

    if (t < 128) csh[t] = 2.0f * sW[s * 128 + t];

    const float* e1base = E1 + (long)(b * 8 + ti * 2) * 16384;
    const float* e2base = E2 + (long)(b * 8 + tj * 2) * 16384;

    float acc[4][4];
#pragma unroll
    for (int i = 0; i < 4; ++i)
#pragma unroll
        for (int j = 0; j < 4; ++j) acc[i][j] = 0.f;

    for (int c0 = 0; c0 < 128; c0 += 32) {
        __syncthreads();
#pragma unroll
        for (int it = 0; it < 2; ++it) {
            const int f = it * 256 + t;
            const int ol = f >> 4;
            const int i4 = (f & 15) * 4;
            const long srcoff = (long)(i4 >> 5) * 16384 + (long)(s * 128 + c0 + ol) * 32 + (i4 & 31);
            *(float4*)&As[ol * 64 + i4] = *(const float4*)(e1base + srcoff);
            *(float4*)&Bs[ol * 64 + i4] = *(const float4*)(e2base + srcoff);
        }
        __syncthreads();

#pragma unroll 2
        for (int p = 0; p < 8; ++p) {
            const float4 c4 = *(const float4*)&csh[c0 + p * 4];
            float4 a0 = *(const float4*)&As[(p * 4 + 0) * 64 + ty * 4];
            float4 a1 = *(const float4*)&As[(p * 4 + 1) * 64 + ty * 4];
            float4 a2 = *(const float4*)&As[(p * 4 + 2) * 64 + ty * 4];
            float4 a3 = *(const float4*)&As[(p * 4 + 3) * 64 + ty * 4];
            float4 b0 = *(const float4*)&Bs[(p * 4 + 0) * 64 + tx * 4];
            float4 b1 = *(const float4*)&Bs[(p * 4 + 1) * 64 + tx * 4];
            float4 b2 = *(const float4*)&Bs[(p * 4 + 2) * 64 + tx * 4];
            float4 b3 = *(const float4*)&Bs[(p * 4 + 3) * 64 + tx * 4];
            const float a0v[4] = {a0.x, a0.y, a0.z, a0.w};
            const float a1v[4] = {a1.x, a1.y, a1.z, a1.w};
            const float a2v[4] = {a2.x, a2.y, a2.z, a2.w};
            const float a3v[4] = {a3.x, a3.y, a3.z, a3.w};
            const float b0v[4] = {b0.x, b0.y, b0.z, b0.w};
            const float b1v[4] = {b1.x, b1.y, b1.z, b1.w};
            const float b2v[4] = {b2.x, b2.y, b2.z, b2.w};
            const float b3v[4] = {b3.x, b3.y, b3.z, b3.w};
#pragma unroll
            for (int i = 0; i < 4; ++i) {
#pragma unroll
                for (int j = 0; j < 4; ++j) {
                    float y0 = fmaf(a0v[i], b0v[j], 1.0f);
                    float y1 = fmaf(a1v[i], b1v[j], 1.0f);
                    float y2 = fmaf(a2v[i], b2v[j], 1.0f);
                    float y3 = fmaf(a3v[i], b3v[j], 1.0f);
                    float y01 = y0 * y1, y23 = y2 * y3;
                    float d = y01 * y23;
                    float n01 = fmaf(c4.x, y1, c4.y * y0);
                    float n23 = fmaf(c4.z, y3, c4.w * y2);
                    float n = fmaf(n01, y23, n23 * y01);
                    acc[i][j] = fmaf(n, fast_rcp(d), acc[i][j]);
                }
            }
        }
    }

    float* Eb = EP + (long)s * 524288 + (long)b * 65536 +
                (long)(ti * 64 + ty * 4) * 256 + tj * 64 + tx * 4;
#pragma unroll
    for (int i = 0; i < 4; ++i)
        *(float4*)&Eb[i * 256] = make_float4(acc[i][0], acc[i][1], acc[i][2], acc[i][3]);

    // ---- last-block softmax for this (b, tj) column group ----
    __threadfence();                                   // release EP writes
    if (t == 0) lastflag = atomicAdd(&cnt[b * 4 + tj], 1u);
    __syncthreads();
    if (lastflag == 15) {
        __threadfence();                               // acquire others' EP writes
        const int jl = t & 63;                         // column within group
        const int q  = t >> 6;                         // i-quarter (64 rows)
        const int jcol = tj * 64 + jl;
        const float* base0 = EP + (long)b * 65536 + jcol;
        float v[64];
        float m = -3.0e38f;
#pragma unroll
        for (int k = 0; k < 64; ++k) {
            const long idx = (long)(q * 64 + k) * 256;
            float sum = base0[idx] + base0[524288 + idx] +
                        base0[1048576 + idx] + base0[1572864 + idx];
            v[k] = -sum;
            m = fmaxf(m, v[k]);
        }
        float* red = As;                               // reuse LDS
        red[t] = m;
        __syncthreads();
        if (t < 64)
            red[t] = fmaxf(fmaxf(red[t], red[t + 64]), fmaxf(red[t + 128], red[t + 192]));
        __syncthreads();
        m = red[jl];
        float ssum = 0.f;
#pragma unroll
        for (int k = 0; k < 64; ++k) {
            v[k] = fast_exp2((v[k] - m) * LOG2E);
            ssum += v[k];
        }
        __syncthreads();                               // red free for reuse
        red[t] = ssum;
        __syncthreads();
        if (t < 64)
            red[t] = (red[t] + red[t + 64]) + (red[t + 128] + red[t + 192]);
        __syncthreads();
        const float inv = fast_rcp(red[jl]);
        float* ob = out + (long)b * 65536 + jcol;
#pragma unroll
        for (int k = 0; k < 64; ++k)
            ob[(long)(q * 64 + k) * 256] = v[k] * inv;
    }
}

extern "C" void kernel_launch(void* const* d_in, const int* in_sizes, int n_in,
                              void* d_out, int out_size, void* d_ws, size_t ws_size,
                              hipStream_t stream) {
    const float* inputs  = (const float*)d_in[0];  // (256, 8, 512)
    const float* attn_W  = (const float*)d_in[1];  // (512, 1024)
    const float* attn_b  = (const float*)d_in[2];  // (512,)
    const float* score_W = (const float*)d_in[3];  // (1, 512)
    float* out = (float*)d_out;                    // (8, 256, 256)

    float* ws = (float*)d_ws;
    float* E1 = ws;                                // 1M f32 exp panel
    float* E2 = ws + (1 << 20);                    // 1M f32
    float* EP = ws + (2 << 20);                    // 4 * 512K f32 partials (8 MB)
    unsigned* cnt = (unsigned*)(ws + (4 << 20));   // 32 counters

    hipMemsetAsync((void*)cnt, 0, 32 * sizeof(unsigned), stream);
    mfma_gemm<<<256, 512, 0, stream>>>(inputs, attn_W, attn_b, E1, E2);
    energy_kernel<<<512, 256, 0, stream>>>(E1, E2, score_W, EP, cnt, out);
}

// Round 22
// 132.337 us; speedup vs baseline: 1.1026x; 1.1026x over previous
//
#include <hip/hip_runtime.h>

#define LOG2E 1.4426950408889634f
#define SCALE (2.0f * LOG2E)

__device__ __forceinline__ float fast_exp2(float x) { return __builtin_amdgcn_exp2f(x); }
__device__ __forceinline__ float fast_rcp(float x)  { return __builtin_amdgcn_rcpf(x); }

typedef __attribute__((ext_vector_type(8))) short bf16x8;
typedef __attribute__((ext_vector_type(4))) float f32x4;

__device__ __forceinline__ void cvt_hilo8(const float* vv, ushort* hi8, ushort* lo8) {
#pragma unroll
    for (int j = 0; j < 8; ++j) {
        unsigned u32 = __float_as_uint(vv[j]);
        unsigned h = (u32 + 0x7FFF + ((u32 >> 16) & 1)) >> 16;   // RN bf16
        hi8[j] = (ushort)h;
        float lo = vv[j] - __uint_as_float(h << 16);
        unsigned ul = __float_as_uint(lo);
        lo8[j] = (ushort)((ul + 0x7FFF + ((ul >> 16) & 1)) >> 16);
    }
}

// ---------------- stage 0+1 fused: MFMA GEMM direct from f32 (R20, unchanged) ----------
__global__ __launch_bounds__(512) void mfma_gemm(const float* __restrict__ inputs,
                                                 const float* __restrict__ attn_W,
                                                 const float* __restrict__ attn_b,
                                                 float* __restrict__ E1,
                                                 float* __restrict__ E2) {
    const int xcd = blockIdx.x & 7;
    const int idx = blockIdx.x >> 3;
    const int mb  = xcd * 2 + (idx >> 4);
    const int nb  = idx & 15;
    __shared__ ushort lds[24576];
    ushort* const Ahi = lds;
    ushort* const Alo = lds + 8192;
    ushort* const Bhi = lds + 16384;
    ushort* const Blo = lds + 20480;

    const int t = threadIdx.x;
    const int lane = t & 63, w = t >> 6;
    const int wr = w >> 1, wc = w & 1;

    const int arow0 = t >> 3, ak8 = t & 7;
    const int arow1 = (t + 512) >> 3;
    const int m0 = mb * 128 + arow0;
    const int m1 = mb * 128 + arow1;
    const float* asrc0 = inputs + (long)((m0 & 255) * 8 + (m0 >> 8)) * 512 + ak8 * 8;
    const float* asrc1 = inputs + (long)((m1 & 255) * 8 + (m1 >> 8)) * 512 + ak8 * 8;
    const int nloc = t >> 3, bk8 = t & 7;
    const int ngl = nb * 64 + nloc;
    const float* bsrc = attn_W + (long)(ngl & 511) * 1024 + (ngl >> 9) * 512 + bk8 * 8;

    const int aoff0 = (arow0 >> 6) * 4096 + (ak8 >> 2) * 2048 + ((arow0 & 63) >> 4) * 512 +
                      ((ak8 & 3) * 16 + (arow0 & 15)) * 8;
    const int aoff1 = (arow1 >> 6) * 4096 + (ak8 >> 2) * 2048 + ((arow1 & 63) >> 4) * 512 +
                      ((ak8 & 3) * 16 + (arow1 & 15)) * 8;
    const int boff  = (bk8 >> 2) * 2048 + (nloc >> 4) * 512 +
                      ((bk8 & 3) * 16 + (nloc & 15)) * 8;

    f32x4 acc[2][2];
#pragma unroll
    for (int i = 0; i < 2; ++i)
#pragma unroll
        for (int j = 0; j < 2; ++j)
            acc[i][j] = (f32x4){0.f, 0.f, 0.f, 0.f};

    float ra0[8], ra1[8], rb[8];
#define LOADF(ss)                                                              \
    {                                                                          \
        *(float4*)&ra0[0] = *(const float4*)(asrc0 + (ss) * 64);               \
        *(float4*)&ra0[4] = *(const float4*)(asrc0 + (ss) * 64 + 4);           \
        *(float4*)&ra1[0] = *(const float4*)(asrc1 + (ss) * 64);               \
        *(float4*)&ra1[4] = *(const float4*)(asrc1 + (ss) * 64 + 4);           \
        *(float4*)&rb[0]  = *(const float4*)(bsrc  + (ss) * 64);               \
        *(float4*)&rb[4]  = *(const float4*)(bsrc  + (ss) * 64 + 4);           \
    }

    LOADF(0);

    for (int ss = 0; ss < 8; ++ss) {
        __syncthreads();
        {
            ushort h8[8], l8[8];
            cvt_hilo8(ra0, h8, l8);
            *(uint4*)&Ahi[aoff0] = *(const uint4*)h8;
            *(uint4*)&Alo[aoff0] = *(const uint4*)l8;
            cvt_hilo8(ra1, h8, l8);
            *(uint4*)&Ahi[aoff1] = *(const uint4*)h8;
            *(uint4*)&Alo[aoff1] = *(const uint4*)l8;
            cvt_hilo8(rb, h8, l8);
            *(uint4*)&Bhi[boff] = *(const uint4*)h8;
            *(uint4*)&Blo[boff] = *(const uint4*)l8;
        }
        if (ss < 7) LOADF(ss + 1);
        __syncthreads();

#pragma unroll
        for (int pass = 0; pass < 3; ++pass) {
            const ushort* Ab = (pass == 1) ? Alo : Ahi;
            const ushort* Bb = (pass == 2) ? Blo : Bhi;
#pragma unroll
            for (int ks = 0; ks < 2; ++ks) {
                bf16x8 a[2], b[2];
                const int abase = (wr >> 1) * 4096 + ks * 2048 + (wr & 1) * 1024 + lane * 8;
                const int bbase = ks * 2048 + wc * 1024 + lane * 8;
                a[0] = *(const bf16x8*)&Ab[abase];
                a[1] = *(const bf16x8*)&Ab[abase + 512];
                b[0] = *(const bf16x8*)&Bb[bbase];
                b[1] = *(const bf16x8*)&Bb[bbase + 512];
#pragma unroll
                for (int mf = 0; mf < 2; ++mf)
#pragma unroll
                    for (int nf = 0; nf < 2; ++nf)
                        acc[mf][nf] = __builtin_amdgcn_mfma_f32_16x16x32_bf16(
                            a[mf], b[nf], acc[mf][nf], 0, 0, 0);
            }
        }
    }
#undef LOADF

#pragma unroll
    for (int nf = 0; nf < 2; ++nf) {
        int n = nb * 64 + wc * 32 + nf * 16 + (lane & 15);
        const bool isE1 = (n < 512);
        float* dst = isE1 ? E1 : E2;
        int o = n & 511;
        float bias = isE1 ? attn_b[o] : 0.0f;
#pragma unroll
        for (int mf = 0; mf < 2; ++mf) {
            int ml = mb * 128 + wr * 32 + mf * 16 + ((lane >> 4) << 2);
            int bb = ml >> 8, l = ml & 255;
            long rowoff = ((long)(bb * 8 + (l >> 5)) * 512 + o) * 32 + (l & 31);
#pragma unroll
            for (int r = 0; r < 4; ++r)
                dst[rowoff + r] = fast_exp2(SCALE * (acc[mf][nf][r] + bias));
        }
    }
}

// ---------------- stage 2: energy v4 + last-block fused softmax (scratch-free tail) ----
// After writing its EP partial, each block fences + bumps a per-(b,tj) counter; the
// 16th arriver runs softmax for its 64 columns in 3 register-light passes over
// L2-hot EP/out (no per-thread arrays -> no scratch). No spinning -> no deadlock.
__global__ __launch_bounds__(256) void energy_kernel(const float* __restrict__ E1,
                                                     const float* __restrict__ E2,
                                                     const float* __restrict__ sW,
                                                     float* __restrict__ EP,
                                                     unsigned* __restrict__ cnt,
                                                     float* __restrict__ out) {
    const int bid = blockIdx.x;       // 512 = s(4) b(8) ti(4) tj(4)
    const int tj = bid & 3;
    const int ti = (bid >> 2) & 3;
    const int b  = (bid >> 4) & 7;
    const int s  = bid >> 7;
    __shared__ float As[32 * 64];
    __shared__ float Bs[32 * 64];
    __shared__ float csh[128];
    __shared__ unsigned lastflag;

    const int t = threadIdx.x;
    const int tx = t & 15, ty = t >> 4;

    if (t < 128) csh[t] = 2.0f * sW[s * 128 + t];

    const float* e1base = E1 + (long)(b * 8 + ti * 2) * 16384;
    const float* e2base = E2 + (long)(b * 8 + tj * 2) * 16384;

    float acc[4][4];
#pragma unroll
    for (int i = 0; i < 4; ++i)
#pragma unroll
        for (int j = 0; j < 4; ++j) acc[i][j] = 0.f;

    for (int c0 = 0; c0 < 128; c0 += 32) {
        __syncthreads();
#pragma unroll
        for (int it = 0; it < 2; ++it) {
            const int f = it * 256 + t;
            const int ol = f >> 4;
            const int i4 = (f & 15) * 4;
            const long srcoff = (long)(i4 >> 5) * 16384 + (long)(s * 128 + c0 + ol) * 32 + (i4 & 31);
            *(float4*)&As[ol * 64 + i4] = *(const float4*)(e1base + srcoff);
            *(float4*)&Bs[ol * 64 + i4] = *(const float4*)(e2base + srcoff);
        }
        __syncthreads();

#pragma unroll 2
        for (int p = 0; p < 8; ++p) {
            const float4 c4 = *(const float4*)&csh[c0 + p * 4];
            float4 a0 = *(const float4*)&As[(p * 4 + 0) * 64 + ty * 4];
            float4 a1 = *(const float4*)&As[(p * 4 + 1) * 64 + ty * 4];
            float4 a2 = *(const float4*)&As[(p * 4 + 2) * 64 + ty * 4];
            float4 a3 = *(const float4*)&As[(p * 4 + 3) * 64 + ty * 4];
            float4 b0 = *(const float4*)&Bs[(p * 4 + 0) * 64 + tx * 4];
            float4 b1 = *(const float4*)&Bs[(p * 4 + 1) * 64 + tx * 4];
            float4 b2 = *(const float4*)&Bs[(p * 4 + 2) * 64 + tx * 4];
            float4 b3 = *(const float4*)&Bs[(p * 4 + 3) * 64 + tx * 4];
            const float a0v[4] = {a0.x, a0.y, a0.z, a0.w};
            const float a1v[4] = {a1.x, a1.y, a1.z, a1.w};
            const float a2v[4] = {a2.x, a2.y, a2.z, a2.w};
            const float a3v[4] = {a3.x, a3.y, a3.z, a3.w};
            const float b0v[4] = {b0.x, b0.y, b0.z, b0.w};
            const float b1v[4] = {b1.x, b1.y, b1.z, b1.w};
            const float b2v[4] = {b2.x, b2.y, b2.z, b2.w};
            const float b3v[4] = {b3.x, b3.y, b3.z, b3.w};
#pragma unroll
            for (int i = 0; i < 4; ++i) {
#pragma unroll
                for (int j = 0; j < 4; ++j) {
                    float y0 = fmaf(a0v[i], b0v[j], 1.0f);
                    float y1 = fmaf(a1v[i], b1v[j], 1.0f);
                    float y2 = fmaf(a2v[i], b2v[j], 1.0f);
                    float y3 = fmaf(a3v[i], b3v[j], 1.0f);
                    float y01 = y0 * y1, y23 = y2 * y3;
                    float d = y01 * y23;
                    float n01 = fmaf(c4.x, y1, c4.y * y0);
                    float n23 = fmaf(c4.z, y3, c4.w * y2);
                    float n = fmaf(n01, y23, n23 * y01);
                    acc[i][j] = fmaf(n, fast_rcp(d), acc[i][j]);
                }
            }
        }
    }

    float* Eb = EP + (long)s * 524288 + (long)b * 65536 +
                (long)(ti * 64 + ty * 4) * 256 + tj * 64 + tx * 4;
#pragma unroll
    for (int i = 0; i < 4; ++i)
        *(float4*)&Eb[i * 256] = make_float4(acc[i][0], acc[i][1], acc[i][2], acc[i][3]);

    // ---- last-block softmax for this (b, tj) column group (scratch-free) ----
    __threadfence();                                   // release EP writes
    if (t == 0) lastflag = atomicAdd(&cnt[b * 4 + tj], 1u);
    __syncthreads();
    if (lastflag == 15) {
        __threadfence();                               // acquire others' EP writes
        const int jl = t & 63;                         // column within group
        const int q  = t >> 6;                         // i-quarter (64 rows each)
        const int jcol = tj * 64 + jl;
        const float* base0 = EP + (long)b * 65536 + jcol;
        float* ob = out + (long)b * 65536 + jcol;
        float* red = As;                               // reuse LDS

        // pass A: max (no storage)
        float m = -3.0e38f;
#pragma unroll 8
        for (int k = 0; k < 64; ++k) {
            const long idx = (long)(q * 64 + k) * 256;
            float sum = base0[idx] + base0[524288 + idx] +
                        base0[1048576 + idx] + base0[1572864 + idx];
            m = fmaxf(m, -sum);
        }
        red[t] = m;
        __syncthreads();
        if (t < 64)
            red[t] = fmaxf(fmaxf(red[t], red[t + 64]), fmaxf(red[t + 128], red[t + 192]));
        __syncthreads();
        m = red[jl];
        __syncthreads();                               // red reused below

        // pass B: exp + sum, store unnormalized exps to out
        float ssum = 0.f;
#pragma unroll 8
        for (int k = 0; k < 64; ++k) {
            const long idx = (long)(q * 64 + k) * 256;
            float sum = base0[idx] + base0[524288 + idx] +
                        base0[1048576 + idx] + base0[1572864 + idx];
            float e = fast_exp2((-sum - m) * LOG2E);
            ssum += e;
            ob[idx] = e;
        }
        red[t] = ssum;
        __syncthreads();
        if (t < 64)
            red[t] = (red[t] + red[t + 64]) + (red[t + 128] + red[t + 192]);
        __syncthreads();
        const float inv = fast_rcp(red[jl]);

        // pass C: normalize in place
#pragma unroll 8
        for (int k = 0; k < 64; ++k) {
            const long idx = (long)(q * 64 + k) * 256;
            ob[idx] *= inv;
        }
    }
}

extern "C" void kernel_launch(void* const* d_in, const int* in_sizes, int n_in,
                              void* d_out, int out_size, void* d_ws, size_t ws_size,
                              hipStream_t stream) {
    const float* inputs  = (const float*)d_in[0];  // (256, 8, 512)
    const float* attn_W  = (const float*)d_in[1];  // (512, 1024)
    const float* attn_b  = (const float*)d_in[2];  // (512,)
    const float* score_W = (const float*)d_in[3];  // (1, 512)
    float* out = (float*)d_out;                    // (8, 256, 256)

    float* ws = (float*)d_ws;
    float* E1 = ws;                                // 1M f32 exp panel
    float* E2 = ws + (1 << 20);                    // 1M f32
    float* EP = ws + (2 << 20);                    // 4 * 512K f32 partials (8 MB)
    unsigned* cnt = (unsigned*)(ws + (4 << 20));   // 32 counters

    hipMemsetAsync((void*)cnt, 0, 32 * sizeof(unsigned), stream);
    mfma_gemm<<<256, 512, 0, stream>>>(inputs, attn_W, attn_b, E1, E2);
    energy_kernel<<<512, 256, 0, stream>>>(E1, E2, score_W, EP, cnt, out);
}

// Round 23
// 76.911 us; speedup vs baseline: 1.8971x; 1.7206x over previous
//
#include <hip/hip_runtime.h>

#define LOG2E 1.4426950408889634f
#define SCALE (2.0f * LOG2E)

__device__ __forceinline__ float fast_exp2(float x) { return __builtin_amdgcn_exp2f(x); }
__device__ __forceinline__ float fast_rcp(float x)  { return __builtin_amdgcn_rcpf(x); }

typedef __attribute__((ext_vector_type(8))) short bf16x8;
typedef __attribute__((ext_vector_type(4))) float f32x4;

__device__ __forceinline__ void cvt_hilo8(const float* vv, ushort* hi8, ushort* lo8) {
#pragma unroll
    for (int j = 0; j < 8; ++j) {
        unsigned u32 = __float_as_uint(vv[j]);
        unsigned h = (u32 + 0x7FFF + ((u32 >> 16) & 1)) >> 16;   // RN bf16
        hi8[j] = (ushort)h;
        float lo = vv[j] - __uint_as_float(h << 16);
        unsigned ul = __float_as_uint(lo);
        lo8[j] = (ushort)((ul + 0x7FFF + ((ul >> 16) & 1)) >> 16);
    }
}

// ---------------- stage 0+1 fused: MFMA GEMM direct from f32 (R20, unchanged) ----------
__global__ __launch_bounds__(512) void mfma_gemm(const float* __restrict__ inputs,
                                                 const float* __restrict__ attn_W,
                                                 const float* __restrict__ attn_b,
                                                 float* __restrict__ E1,
                                                 float* __restrict__ E2) {
    const int xcd = blockIdx.x & 7;
    const int idx = blockIdx.x >> 3;
    const int mb  = xcd * 2 + (idx >> 4);
    const int nb  = idx & 15;
    __shared__ ushort lds[24576];
    ushort* const Ahi = lds;
    ushort* const Alo = lds + 8192;
    ushort* const Bhi = lds + 16384;
    ushort* const Blo = lds + 20480;

    const int t = threadIdx.x;
    const int lane = t & 63, w = t >> 6;
    const int wr = w >> 1, wc = w & 1;

    const int arow0 = t >> 3, ak8 = t & 7;
    const int arow1 = (t + 512) >> 3;
    const int m0 = mb * 128 + arow0;
    const int m1 = mb * 128 + arow1;
    const float* asrc0 = inputs + (long)((m0 & 255) * 8 + (m0 >> 8)) * 512 + ak8 * 8;
    const float* asrc1 = inputs + (long)((m1 & 255) * 8 + (m1 >> 8)) * 512 + ak8 * 8;
    const int nloc = t >> 3, bk8 = t & 7;
    const int ngl = nb * 64 + nloc;
    const float* bsrc = attn_W + (long)(ngl & 511) * 1024 + (ngl >> 9) * 512 + bk8 * 8;

    const int aoff0 = (arow0 >> 6) * 4096 + (ak8 >> 2) * 2048 + ((arow0 & 63) >> 4) * 512 +
                      ((ak8 & 3) * 16 + (arow0 & 15)) * 8;
    const int aoff1 = (arow1 >> 6) * 4096 + (ak8 >> 2) * 2048 + ((arow1 & 63) >> 4) * 512 +
                      ((ak8 & 3) * 16 + (arow1 & 15)) * 8;
    const int boff  = (bk8 >> 2) * 2048 + (nloc >> 4) * 512 +
                      ((bk8 & 3) * 16 + (nloc & 15)) * 8;

    f32x4 acc[2][2];
#pragma unroll
    for (int i = 0; i < 2; ++i)
#pragma unroll
        for (int j = 0; j < 2; ++j)
            acc[i][j] = (f32x4){0.f, 0.f, 0.f, 0.f};

    float ra0[8], ra1[8], rb[8];
#define LOADF(ss)                                                              \
    {                                                                          \
        *(float4*)&ra0[0] = *(const float4*)(asrc0 + (ss) * 64);               \
        *(float4*)&ra0[4] = *(const float4*)(asrc0 + (ss) * 64 + 4);           \
        *(float4*)&ra1[0] = *(const float4*)(asrc1 + (ss) * 64);               \
        *(float4*)&ra1[4] = *(const float4*)(asrc1 + (ss) * 64 + 4);           \
        *(float4*)&rb[0]  = *(const float4*)(bsrc  + (ss) * 64);               \
        *(float4*)&rb[4]  = *(const float4*)(bsrc  + (ss) * 64 + 4);           \
    }

    LOADF(0);

    for (int ss = 0; ss < 8; ++ss) {
        __syncthreads();
        {
            ushort h8[8], l8[8];
            cvt_hilo8(ra0, h8, l8);
            *(uint4*)&Ahi[aoff0] = *(const uint4*)h8;
            *(uint4*)&Alo[aoff0] = *(const uint4*)l8;
            cvt_hilo8(ra1, h8, l8);
            *(uint4*)&Ahi[aoff1] = *(const uint4*)h8;
            *(uint4*)&Alo[aoff1] = *(const uint4*)l8;
            cvt_hilo8(rb, h8, l8);
            *(uint4*)&Bhi[boff] = *(const uint4*)h8;
            *(uint4*)&Blo[boff] = *(const uint4*)l8;
        }
        if (ss < 7) LOADF(ss + 1);
        __syncthreads();

#pragma unroll
        for (int pass = 0; pass < 3; ++pass) {
            const ushort* Ab = (pass == 1) ? Alo : Ahi;
            const ushort* Bb = (pass == 2) ? Blo : Bhi;
#pragma unroll
            for (int ks = 0; ks < 2; ++ks) {
                bf16x8 a[2], b[2];
                const int abase = (wr >> 1) * 4096 + ks * 2048 + (wr & 1) * 1024 + lane * 8;
                const int bbase = ks * 2048 + wc * 1024 + lane * 8;
                a[0] = *(const bf16x8*)&Ab[abase];
                a[1] = *(const bf16x8*)&Ab[abase + 512];
                b[0] = *(const bf16x8*)&Bb[bbase];
                b[1] = *(const bf16x8*)&Bb[bbase + 512];
#pragma unroll
                for (int mf = 0; mf < 2; ++mf)
#pragma unroll
                    for (int nf = 0; nf < 2; ++nf)
                        acc[mf][nf] = __builtin_amdgcn_mfma_f32_16x16x32_bf16(
                            a[mf], b[nf], acc[mf][nf], 0, 0, 0);
            }
        }
    }
#undef LOADF

#pragma unroll
    for (int nf = 0; nf < 2; ++nf) {
        int n = nb * 64 + wc * 32 + nf * 16 + (lane & 15);
        const bool isE1 = (n < 512);
        float* dst = isE1 ? E1 : E2;
        int o = n & 511;
        float bias = isE1 ? attn_b[o] : 0.0f;
#pragma unroll
        for (int mf = 0; mf < 2; ++mf) {
            int ml = mb * 128 + wr * 32 + mf * 16 + ((lane >> 4) << 2);
            int bb = ml >> 8, l = ml & 255;
            long rowoff = ((long)(bb * 8 + (l >> 5)) * 512 + o) * 32 + (l & 31);
#pragma unroll
            for (int r = 0; r < 4; ++r)
                dst[rowoff + r] = fast_exp2(SCALE * (acc[mf][nf][r] + bias));
        }
    }
}

// ---------------- stage 2: partial energies v5 (8-way exact rcp combine) ----------------
// EP[s][b][i][j] = sum_{o in chunk s (128)} c_o * rcp(1 + E1[b,i,o]*E2[b,j,o])
// 64i x 64j tile, 4x4/thread, [o][i] LDS (32-o chunks). 8-way tree (y>1 always):
//   d8 = prod y_q ; n8 = n4a*d4b + n4b*d4a ; n4 = n01*y23 + n23*y01 ; n01 = c0y1+c1y0
__global__ __launch_bounds__(256) void energy_kernel(const float* __restrict__ E1,
                                                     const float* __restrict__ E2,
                                                     const float* __restrict__ sW,
                                                     float* __restrict__ EP) {
    const int bid = blockIdx.x;       // 512 = s(4) b(8) ti(4) tj(4)
    const int tj = bid & 3;
    const int ti = (bid >> 2) & 3;
    const int b  = (bid >> 4) & 7;
    const int s  = bid >> 7;
    __shared__ float As[32 * 64];
    __shared__ float Bs[32 * 64];
    __shared__ float csh[128];

    const int t = threadIdx.x;
    const int tx = t & 15, ty = t >> 4;

    if (t < 128) csh[t] = 2.0f * sW[s * 128 + t];

    const float* e1base = E1 + (long)(b * 8 + ti * 2) * 16384;
    const float* e2base = E2 + (long)(b * 8 + tj * 2) * 16384;

    float acc[4][4];
#pragma unroll
    for (int i = 0; i < 4; ++i)
#pragma unroll
        for (int j = 0; j < 4; ++j) acc[i][j] = 0.f;

    for (int c0 = 0; c0 < 128; c0 += 32) {
        __syncthreads();
#pragma unroll
        for (int it = 0; it < 2; ++it) {
            const int f = it * 256 + t;
            const int ol = f >> 4;
            const int i4 = (f & 15) * 4;
            const long srcoff = (long)(i4 >> 5) * 16384 + (long)(s * 128 + c0 + ol) * 32 + (i4 & 31);
            *(float4*)&As[ol * 64 + i4] = *(const float4*)(e1base + srcoff);
            *(float4*)&Bs[ol * 64 + i4] = *(const float4*)(e2base + srcoff);
        }
        __syncthreads();

#pragma unroll
        for (int p = 0; p < 4; ++p) {            // 4 o-octets per chunk
            const float4 cA = *(const float4*)&csh[c0 + p * 8];
            const float4 cB = *(const float4*)&csh[c0 + p * 8 + 4];
            float4 av[8], bv[8];
#pragma unroll
            for (int r = 0; r < 8; ++r) {
                av[r] = *(const float4*)&As[(p * 8 + r) * 64 + ty * 4];
                bv[r] = *(const float4*)&Bs[(p * 8 + r) * 64 + tx * 4];
            }
            const float* a0v = (const float*)&av[0];
            const float* a1v = (const float*)&av[1];
            const float* a2v = (const float*)&av[2];
            const float* a3v = (const float*)&av[3];
            const float* a4v = (const float*)&av[4];
            const float* a5v = (const float*)&av[5];
            const float* a6v = (const float*)&av[6];
            const float* a7v = (const float*)&av[7];
            const float* b0v = (const float*)&bv[0];
            const float* b1v = (const float*)&bv[1];
            const float* b2v = (const float*)&bv[2];
            const float* b3v = (const float*)&bv[3];
            const float* b4v = (const float*)&bv[4];
            const float* b5v = (const float*)&bv[5];
            const float* b6v = (const float*)&bv[6];
            const float* b7v = (const float*)&bv[7];
#pragma unroll
            for (int i = 0; i < 4; ++i) {
#pragma unroll
                for (int j = 0; j < 4; ++j) {
                    float y0 = fmaf(a0v[i], b0v[j], 1.0f);
                    float y1 = fmaf(a1v[i], b1v[j], 1.0f);
                    float y2 = fmaf(a2v[i], b2v[j], 1.0f);
                    float y3 = fmaf(a3v[i], b3v[j], 1.0f);
                    float y4 = fmaf(a4v[i], b4v[j], 1.0f);
                    float y5 = fmaf(a5v[i], b5v[j], 1.0f);
                    float y6 = fmaf(a6v[i], b6v[j], 1.0f);
                    float y7 = fmaf(a7v[i], b7v[j], 1.0f);
                    float y01 = y0 * y1, y23 = y2 * y3;
                    float y45 = y4 * y5, y67 = y6 * y7;
                    float d4a = y01 * y23, d4b = y45 * y67;
                    float n01 = fmaf(cA.x, y1, cA.y * y0);
                    float n23 = fmaf(cA.z, y3, cA.w * y2);
                    float n45 = fmaf(cB.x, y5, cB.y * y4);
                    float n67 = fmaf(cB.z, y7, cB.w * y6);
                    float n4a = fmaf(n01, y23, n23 * y01);
                    float n4b = fmaf(n45, y67, n67 * y45);
                    float d8 = d4a * d4b;
                    float n8 = fmaf(n4a, d4b, n4b * d4a);
                    acc[i][j] = fmaf(n8, fast_rcp(d8), acc[i][j]);
                }
            }
        }
    }

    float* Eb = EP + (long)s * 524288 + (long)b * 65536 +
                (long)(ti * 64 + ty * 4) * 256 + tj * 64 + tx * 4;
#pragma unroll
    for (int i = 0; i < 4; ++i)
        *(float4*)&Eb[i * 256] = make_float4(acc[i][0], acc[i][1], acc[i][2], acc[i][3]);
}

// ---------------- stage 3: combine partials + softmax over i (axis=1) ----------------
__global__ __launch_bounds__(256) void softmax_kernel(const float* __restrict__ P0,
                                                      const float* __restrict__ P1,
                                                      const float* __restrict__ P2,
                                                      const float* __restrict__ P3,
                                                      float* __restrict__ out) {
    const int b  = blockIdx.x >> 4;
    const int jt = blockIdx.x & 15;
    const int t  = threadIdx.x;
    const int jx = t & 15;
    const int iy = t >> 4;
    const long base = (long)b * 65536 + jt * 16 + jx;

    float v[16];
#pragma unroll
    for (int k = 0; k < 16; ++k) {
        long idx = base + (long)(iy + k * 16) * 256;
        v[k] = -(P0[idx] + P1[idx] + P2[idx] + P3[idx]);
    }

    float m = v[0];
#pragma unroll
    for (int k = 1; k < 16; ++k) m = fmaxf(m, v[k]);

    __shared__ float red[256];
    red[t] = m;
    __syncthreads();
    if (t < 128) red[t] = fmaxf(red[t], red[t + 128]);
    __syncthreads();
    if (t < 64) red[t] = fmaxf(red[t], red[t + 64]);
    __syncthreads();
    if (t < 32) red[t] = fmaxf(red[t], red[t + 32]);
    __syncthreads();
    if (t < 16) red[t] = fmaxf(red[t], red[t + 16]);
    __syncthreads();
    m = red[jx];
    __syncthreads();

    float ssum = 0.f;
#pragma unroll
    for (int k = 0; k < 16; ++k) {
        v[k] = fast_exp2((v[k] - m) * LOG2E);
        ssum += v[k];
    }
    red[t] = ssum;
    __syncthreads();
    if (t < 128) red[t] += red[t + 128];
    __syncthreads();
    if (t < 64) red[t] += red[t + 64];
    __syncthreads();
    if (t < 32) red[t] += red[t + 32];
    __syncthreads();
    if (t < 16) red[t] += red[t + 16];
    __syncthreads();
    float inv = fast_rcp(red[jx]);

#pragma unroll
    for (int k = 0; k < 16; ++k) {
        long idx = base + (long)(iy + k * 16) * 256;
        out[idx] = v[k] * inv;
    }
}

extern "C" void kernel_launch(void* const* d_in, const int* in_sizes, int n_in,
                              void* d_out, int out_size, void* d_ws, size_t ws_size,
                              hipStream_t stream) {
    const float* inputs  = (const float*)d_in[0];  // (256, 8, 512)
    const float* attn_W  = (const float*)d_in[1];  // (512, 1024)
    const float* attn_b  = (const float*)d_in[2];  // (512,)
    const float* score_W = (const float*)d_in[3];  // (1, 512)
    float* out = (float*)d_out;                    // (8, 256, 256)

    float* ws = (float*)d_ws;
    float* E1 = ws;                                // 1M f32 exp panel
    float* E2 = ws + (1 << 20);                    // 1M f32
    float* EP = ws + (2 << 20);                    // 4 * 512K f32 partials (8 MB)

    mfma_gemm<<<256, 512, 0, stream>>>(inputs, attn_W, attn_b, E1, E2);
    energy_kernel<<<512, 256, 0, stream>>>(E1, E2, score_W, EP);
    softmax_kernel<<<128, 256, 0, stream>>>(EP, EP + 524288, EP + 2 * 524288,
                                            EP + 3 * 524288, out);
}

// Round 24
// 53.037 us; speedup vs baseline: 2.7511x; 1.4502x over previous
//
#include <hip/hip_runtime.h>

#define LOG2E 1.4426950408889634f
#define SCALE (2.0f * LOG2E)

__device__ __forceinline__ float fast_exp2(float x) { return __builtin_amdgcn_exp2f(x); }
__device__ __forceinline__ float fast_rcp(float x)  { return __builtin_amdgcn_rcpf(x); }

typedef __attribute__((ext_vector_type(8))) short bf16x8;
typedef __attribute__((ext_vector_type(4))) float f32x4;

__device__ __forceinline__ void cvt_hilo8(const float* vv, ushort* hi8, ushort* lo8) {
#pragma unroll
    for (int j = 0; j < 8; ++j) {
        unsigned u32 = __float_as_uint(vv[j]);
        unsigned h = (u32 + 0x7FFF + ((u32 >> 16) & 1)) >> 16;   // RN bf16
        hi8[j] = (ushort)h;
        float lo = vv[j] - __uint_as_float(h << 16);
        unsigned ul = __float_as_uint(lo);
        lo8[j] = (ushort)((ul + 0x7FFF + ((ul >> 16) & 1)) >> 16);
    }
}

// ---------------- stage 0+1 fused: MFMA GEMM direct from f32 (R20, unchanged) ----------
__global__ __launch_bounds__(512) void mfma_gemm(const float* __restrict__ inputs,
                                                 const float* __restrict__ attn_W,
                                                 const float* __restrict__ attn_b,
                                                 float* __restrict__ E1,
                                                 float* __restrict__ E2) {
    const int xcd = blockIdx.x & 7;
    const int idx = blockIdx.x >> 3;
    const int mb  = xcd * 2 + (idx >> 4);
    const int nb  = idx & 15;
    __shared__ ushort lds[24576];
    ushort* const Ahi = lds;
    ushort* const Alo = lds + 8192;
    ushort* const Bhi = lds + 16384;
    ushort* const Blo = lds + 20480;

    const int t = threadIdx.x;
    const int lane = t & 63, w = t >> 6;
    const int wr = w >> 1, wc = w & 1;

    const int arow0 = t >> 3, ak8 = t & 7;
    const int arow1 = (t + 512) >> 3;
    const int m0 = mb * 128 + arow0;
    const int m1 = mb * 128 + arow1;
    const float* asrc0 = inputs + (long)((m0 & 255) * 8 + (m0 >> 8)) * 512 + ak8 * 8;
    const float* asrc1 = inputs + (long)((m1 & 255) * 8 + (m1 >> 8)) * 512 + ak8 * 8;
    const int nloc = t >> 3, bk8 = t & 7;
    const int ngl = nb * 64 + nloc;
    const float* bsrc = attn_W + (long)(ngl & 511) * 1024 + (ngl >> 9) * 512 + bk8 * 8;

    const int aoff0 = (arow0 >> 6) * 4096 + (ak8 >> 2) * 2048 + ((arow0 & 63) >> 4) * 512 +
                      ((ak8 & 3) * 16 + (arow0 & 15)) * 8;
    const int aoff1 = (arow1 >> 6) * 4096 + (ak8 >> 2) * 2048 + ((arow1 & 63) >> 4) * 512 +
                      ((ak8 & 3) * 16 + (arow1 & 15)) * 8;
    const int boff  = (bk8 >> 2) * 2048 + (nloc >> 4) * 512 +
                      ((bk8 & 3) * 16 + (nloc & 15)) * 8;

    f32x4 acc[2][2];
#pragma unroll
    for (int i = 0; i < 2; ++i)
#pragma unroll
        for (int j = 0; j < 2; ++j)
            acc[i][j] = (f32x4){0.f, 0.f, 0.f, 0.f};

    float ra0[8], ra1[8], rb[8];
#define LOADF(ss)                                                              \
    {                                                                          \
        *(float4*)&ra0[0] = *(const float4*)(asrc0 + (ss) * 64);               \
        *(float4*)&ra0[4] = *(const float4*)(asrc0 + (ss) * 64 + 4);           \
        *(float4*)&ra1[0] = *(const float4*)(asrc1 + (ss) * 64);               \
        *(float4*)&ra1[4] = *(const float4*)(asrc1 + (ss) * 64 + 4);           \
        *(float4*)&rb[0]  = *(const float4*)(bsrc  + (ss) * 64);               \
        *(float4*)&rb[4]  = *(const float4*)(bsrc  + (ss) * 64 + 4);           \
    }

    LOADF(0);

    for (int ss = 0; ss < 8; ++ss) {
        __syncthreads();
        {
            ushort h8[8], l8[8];
            cvt_hilo8(ra0, h8, l8);
            *(uint4*)&Ahi[aoff0] = *(const uint4*)h8;
            *(uint4*)&Alo[aoff0] = *(const uint4*)l8;
            cvt_hilo8(ra1, h8, l8);
            *(uint4*)&Ahi[aoff1] = *(const uint4*)h8;
            *(uint4*)&Alo[aoff1] = *(const uint4*)l8;
            cvt_hilo8(rb, h8, l8);
            *(uint4*)&Bhi[boff] = *(const uint4*)h8;
            *(uint4*)&Blo[boff] = *(const uint4*)l8;
        }
        if (ss < 7) LOADF(ss + 1);
        __syncthreads();

#pragma unroll
        for (int pass = 0; pass < 3; ++pass) {
            const ushort* Ab = (pass == 1) ? Alo : Ahi;
            const ushort* Bb = (pass == 2) ? Blo : Bhi;
#pragma unroll
            for (int ks = 0; ks < 2; ++ks) {
                bf16x8 a[2], b[2];
                const int abase = (wr >> 1) * 4096 + ks * 2048 + (wr & 1) * 1024 + lane * 8;
                const int bbase = ks * 2048 + wc * 1024 + lane * 8;
                a[0] = *(const bf16x8*)&Ab[abase];
                a[1] = *(const bf16x8*)&Ab[abase + 512];
                b[0] = *(const bf16x8*)&Bb[bbase];
                b[1] = *(const bf16x8*)&Bb[bbase + 512];
#pragma unroll
                for (int mf = 0; mf < 2; ++mf)
#pragma unroll
                    for (int nf = 0; nf < 2; ++nf)
                        acc[mf][nf] = __builtin_amdgcn_mfma_f32_16x16x32_bf16(
                            a[mf], b[nf], acc[mf][nf], 0, 0, 0);
            }
        }
    }
#undef LOADF

#pragma unroll
    for (int nf = 0; nf < 2; ++nf) {
        int n = nb * 64 + wc * 32 + nf * 16 + (lane & 15);
        const bool isE1 = (n < 512);
        float* dst = isE1 ? E1 : E2;
        int o = n & 511;
        float bias = isE1 ? attn_b[o] : 0.0f;
#pragma unroll
        for (int mf = 0; mf < 2; ++mf) {
            int ml = mb * 128 + wr * 32 + mf * 16 + ((lane >> 4) << 2);
            int bb = ml >> 8, l = ml & 255;
            long rowoff = ((long)(bb * 8 + (l >> 5)) * 512 + o) * 32 + (l & 31);
#pragma unroll
            for (int r = 0; r < 4; ++r)
                dst[rowoff + r] = fast_exp2(SCALE * (acc[mf][nf][r] + bias));
        }
    }
}

// ---------------- stage 2: partial energies v4 + reg-dbuf staging ----------------
// EP[s][b][i][j] = sum_{o in chunk s (128)} c_o * rcp(1 + E1[b,i,o]*E2[b,j,o])
// 64i x 64j tile, 4x4/thread, [o][i] LDS (32-o chunks), 4-way exact rcp combine.
// Next chunk preloaded into registers during current compute (hides L2 latency).
__global__ __launch_bounds__(256) void energy_kernel(const float* __restrict__ E1,
                                                     const float* __restrict__ E2,
                                                     const float* __restrict__ sW,
                                                     float* __restrict__ EP) {
    const int bid = blockIdx.x;       // 512 = s(4) b(8) ti(4) tj(4)
    const int tj = bid & 3;
    const int ti = (bid >> 2) & 3;
    const int b  = (bid >> 4) & 7;
    const int s  = bid >> 7;
    __shared__ float As[32 * 64];
    __shared__ float Bs[32 * 64];
    __shared__ float csh[128];

    const int t = threadIdx.x;
    const int tx = t & 15, ty = t >> 4;

    if (t < 128) csh[t] = 2.0f * sW[s * 128 + t];

    const float* e1base = E1 + (long)(b * 8 + ti * 2) * 16384;
    const float* e2base = E2 + (long)(b * 8 + tj * 2) * 16384;

    // staging geometry: 2 units/thread, unit f -> ol=f>>4, i4=(f&15)*4
    const int f0 = t, f1 = 256 + t;
    const int ol0 = f0 >> 4, i40 = (f0 & 15) * 4;
    const int ol1 = f1 >> 4, i41 = (f1 & 15) * 4;
    const long sb0 = (long)(i40 >> 5) * 16384 + (long)(s * 128 + ol0) * 32 + (i40 & 31);
    const long sb1 = (long)(i41 >> 5) * 16384 + (long)(s * 128 + ol1) * 32 + (i41 & 31);

    float4 pa0, pa1, pb0, pb1;
#define LOADE(c0)                                                   \
    {                                                               \
        pa0 = *(const float4*)(e1base + sb0 + (long)(c0) * 32);     \
        pa1 = *(const float4*)(e1base + sb1 + (long)(c0) * 32);     \
        pb0 = *(const float4*)(e2base + sb0 + (long)(c0) * 32);     \
        pb1 = *(const float4*)(e2base + sb1 + (long)(c0) * 32);     \
    }

    float acc[4][4];
#pragma unroll
    for (int i = 0; i < 4; ++i)
#pragma unroll
        for (int j = 0; j < 4; ++j) acc[i][j] = 0.f;

    LOADE(0);

    for (int c0 = 0; c0 < 128; c0 += 32) {
        __syncthreads();
        *(float4*)&As[ol0 * 64 + i40] = pa0;
        *(float4*)&As[ol1 * 64 + i41] = pa1;
        *(float4*)&Bs[ol0 * 64 + i40] = pb0;
        *(float4*)&Bs[ol1 * 64 + i41] = pb1;
        if (c0 < 96) LOADE(c0 + 32);   // drains under compute below
        __syncthreads();

#pragma unroll 2
        for (int p = 0; p < 8; ++p) {            // 8 o-quads per chunk
            const float4 c4 = *(const float4*)&csh[c0 + p * 4];
            float4 a0 = *(const float4*)&As[(p * 4 + 0) * 64 + ty * 4];
            float4 a1 = *(const float4*)&As[(p * 4 + 1) * 64 + ty * 4];
            float4 a2 = *(const float4*)&As[(p * 4 + 2) * 64 + ty * 4];
            float4 a3 = *(const float4*)&As[(p * 4 + 3) * 64 + ty * 4];
            float4 b0 = *(const float4*)&Bs[(p * 4 + 0) * 64 + tx * 4];
            float4 b1 = *(const float4*)&Bs[(p * 4 + 1) * 64 + tx * 4];
            float4 b2 = *(const float4*)&Bs[(p * 4 + 2) * 64 + tx * 4];
            float4 b3 = *(const float4*)&Bs[(p * 4 + 3) * 64 + tx * 4];
            const float a0v[4] = {a0.x, a0.y, a0.z, a0.w};
            const float a1v[4] = {a1.x, a1.y, a1.z, a1.w};
            const float a2v[4] = {a2.x, a2.y, a2.z, a2.w};
            const float a3v[4] = {a3.x, a3.y, a3.z, a3.w};
            const float b0v[4] = {b0.x, b0.y, b0.z, b0.w};
            const float b1v[4] = {b1.x, b1.y, b1.z, b1.w};
            const float b2v[4] = {b2.x, b2.y, b2.z, b2.w};
            const float b3v[4] = {b3.x, b3.y, b3.z, b3.w};
#pragma unroll
            for (int i = 0; i < 4; ++i) {
#pragma unroll
                for (int j = 0; j < 4; ++j) {
                    float y0 = fmaf(a0v[i], b0v[j], 1.0f);
                    float y1 = fmaf(a1v[i], b1v[j], 1.0f);
                    float y2 = fmaf(a2v[i], b2v[j], 1.0f);
                    float y3 = fmaf(a3v[i], b3v[j], 1.0f);
                    float y01 = y0 * y1, y23 = y2 * y3;
                    float d = y01 * y23;
                    float n01 = fmaf(c4.x, y1, c4.y * y0);
                    float n23 = fmaf(c4.z, y3, c4.w * y2);
                    float n = fmaf(n01, y23, n23 * y01);
                    acc[i][j] = fmaf(n, fast_rcp(d), acc[i][j]);
                }
            }
        }
    }
#undef LOADE

    float* Eb = EP + (long)s * 524288 + (long)b * 65536 +
                (long)(ti * 64 + ty * 4) * 256 + tj * 64 + tx * 4;
#pragma unroll
    for (int i = 0; i < 4; ++i)
        *(float4*)&Eb[i * 256] = make_float4(acc[i][0], acc[i][1], acc[i][2], acc[i][3]);
}

// ---------------- stage 3: combine partials + softmax over i (axis=1) ----------------
__global__ __launch_bounds__(256) void softmax_kernel(const float* __restrict__ P0,
                                                      const float* __restrict__ P1,
                                                      const float* __restrict__ P2,
                                                      const float* __restrict__ P3,
                                                      float* __restrict__ out) {
    const int b  = blockIdx.x >> 4;
    const int jt = blockIdx.x & 15;
    const int t  = threadIdx.x;
    const int jx = t & 15;
    const int iy = t >> 4;
    const long base = (long)b * 65536 + jt * 16 + jx;

    float v[16];
#pragma unroll
    for (int k = 0; k < 16; ++k) {
        long idx = base + (long)(iy + k * 16) * 256;
        v[k] = -(P0[idx] + P1[idx] + P2[idx] + P3[idx]);
    }

    float m = v[0];
#pragma unroll
    for (int k = 1; k < 16; ++k) m = fmaxf(m, v[k]);

    __shared__ float red[256];
    red[t] = m;
    __syncthreads();
    if (t < 128) red[t] = fmaxf(red[t], red[t + 128]);
    __syncthreads();
    if (t < 64) red[t] = fmaxf(red[t], red[t + 64]);
    __syncthreads();
    if (t < 32) red[t] = fmaxf(red[t], red[t + 32]);
    __syncthreads();
    if (t < 16) red[t] = fmaxf(red[t], red[t + 16]);
    __syncthreads();
    m = red[jx];
    __syncthreads();

    float ssum = 0.f;
#pragma unroll
    for (int k = 0; k < 16; ++k) {
        v[k] = fast_exp2((v[k] - m) * LOG2E);
        ssum += v[k];
    }
    red[t] = ssum;
    __syncthreads();
    if (t < 128) red[t] += red[t + 128];
    __syncthreads();
    if (t < 64) red[t] += red[t + 64];
    __syncthreads();
    if (t < 32) red[t] += red[t + 32];
    __syncthreads();
    if (t < 16) red[t] += red[t + 16];
    __syncthreads();
    float inv = fast_rcp(red[jx]);

#pragma unroll
    for (int k = 0; k < 16; ++k) {
        long idx = base + (long)(iy + k * 16) * 256;
        out[idx] = v[k] * inv;
    }
}

extern "C" void kernel_launch(void* const* d_in, const int* in_sizes, int n_in,
                              void* d_out, int out_size, void* d_ws, size_t ws_size,
                              hipStream_t stream) {
    const float* inputs  = (const float*)d_in[0];  // (256, 8, 512)
    const float* attn_W  = (const float*)d_in[1];  // (512, 1024)
    const float* attn_b  = (const float*)d_in[2];  // (512,)
    const float* score_W = (const float*)d_in[3];  // (1, 512)
    float* out = (float*)d_out;                    // (8, 256, 256)

    float* ws = (float*)d_ws;
    float* E1 = ws;                                // 1M f32 exp panel
    float* E2 = ws + (1 << 20);                    // 1M f32
    float* EP = ws + (2 << 20);                    // 4 * 512K f32 partials (8 MB)

    mfma_gemm<<<256, 512, 0, stream>>>(inputs, attn_W, attn_b, E1, E2);
    energy_kernel<<<512, 256, 0, stream>>>(E1, E2, score_W, EP);
    softmax_kernel<<<128, 256, 0, stream>>>(EP, EP + 524288, EP + 2 * 524288,
                                            EP + 3 * 524288, out);
}